// Round 1
// baseline (1376.207 us; speedup 1.0000x reference)
//
#include <hip/hip_runtime.h>
#include <math.h>

// Problem constants (from reference)
constexpr int T  = 16384;   // tokens
constexpr int D  = 7168;    // hidden dim
constexpr int E  = 256;     // experts
constexpr int NG = 8;       // n_groups
constexpr int GS = 32;      // experts per group (E/NG)
constexpr int TOPK_G = 4;
constexpr int TOPK   = 8;

// Tiling
constexpr int BM = 64;      // rows per block
constexpr int BK = 16;      // k-chunk
constexpr int NT = 256;     // threads per block

// LDS strides (floats)
constexpr int AS_S = 68;    // 64 + 4 pad
constexpr int BS_S = 260;   // 256 + 4 pad
constexpr int SC_S = 257;   // 256 + 1 pad -> conflict-free per-row scans

__global__ __launch_bounds__(NT, 1)
void gate_fused(const float* __restrict__ X, const float* __restrict__ W,
                float* __restrict__ out) {
    __shared__ float As[BK * AS_S];   //  4.35 KB  A tile, [k][row]
    __shared__ float Bs[BK * BS_S];   // 16.64 KB  B tile, [k][expert]
    __shared__ float Sc[BM * SC_S];   // 65.79 KB  logits/scores [row][expert]

    const int tid  = threadIdx.x;
    const int row0 = blockIdx.x * BM;

    // ---- global->LDS staging mapping (one float4 of A, four of B per thread) ----
    const int lrow = tid >> 2;          // 0..63
    const int kq4  = (tid & 3) << 2;    // 0,4,8,12  (k offset within chunk)

    const float* aptr = X + (size_t)(row0 + lrow) * D + kq4;
    const float* bptr = W + (size_t)lrow * D + kq4;

    // ---- micro-tile mapping: 8x8 outputs per thread ----
    const int ty = tid >> 5;            // 0..7  -> rows ty*4..+3 and 32+ty*4..+3
    const int tx = tid & 31;            // 0..31 -> cols tx*4..+3 and 128+tx*4..+3

    float acc[8][8];
#pragma unroll
    for (int i = 0; i < 8; ++i)
#pragma unroll
        for (int j = 0; j < 8; ++j) acc[i][j] = 0.0f;

    // prefetch chunk 0
    float4 areg  = *(const float4*)aptr;
    float4 breg0 = *(const float4*)(bptr);
    float4 breg1 = *(const float4*)(bptr + (size_t)64  * D);
    float4 breg2 = *(const float4*)(bptr + (size_t)128 * D);
    float4 breg3 = *(const float4*)(bptr + (size_t)192 * D);
    aptr += BK; bptr += BK;

    constexpr int NKT = D / BK;   // 448
    for (int kt = 0; kt < NKT; ++kt) {
        __syncthreads();   // previous chunk's compute done reading LDS
        // store staged regs to LDS (transposed to [k][m])
        {
            const float* a = (const float*)&areg;
            const float* b0 = (const float*)&breg0;
            const float* b1 = (const float*)&breg1;
            const float* b2 = (const float*)&breg2;
            const float* b3 = (const float*)&breg3;
#pragma unroll
            for (int j = 0; j < 4; ++j) {
                As[(kq4 + j) * AS_S + lrow]        = a[j];
                Bs[(kq4 + j) * BS_S + lrow]        = b0[j];
                Bs[(kq4 + j) * BS_S + 64  + lrow]  = b1[j];
                Bs[(kq4 + j) * BS_S + 128 + lrow]  = b2[j];
                Bs[(kq4 + j) * BS_S + 192 + lrow]  = b3[j];
            }
        }
        __syncthreads();
        // prefetch next chunk (hidden under this chunk's ~2048 compute cycles)
        if (kt + 1 < NKT) {
            areg  = *(const float4*)aptr;
            breg0 = *(const float4*)(bptr);
            breg1 = *(const float4*)(bptr + (size_t)64  * D);
            breg2 = *(const float4*)(bptr + (size_t)128 * D);
            breg3 = *(const float4*)(bptr + (size_t)192 * D);
            aptr += BK; bptr += BK;
        }

        // compute: two-level accumulation (c2 per chunk) for fp32 fidelity
        float c2[8][8];
#pragma unroll
        for (int k = 0; k < BK; ++k) {
            float af[8], bf[8];
            *(float4*)&af[0] = *(const float4*)&As[k * AS_S + (ty << 2)];
            *(float4*)&af[4] = *(const float4*)&As[k * AS_S + 32 + (ty << 2)];
            *(float4*)&bf[0] = *(const float4*)&Bs[k * BS_S + (tx << 2)];
            *(float4*)&bf[4] = *(const float4*)&Bs[k * BS_S + 128 + (tx << 2)];
#pragma unroll
            for (int i = 0; i < 8; ++i)
#pragma unroll
                for (int j = 0; j < 8; ++j) {
                    if (k == 0) c2[i][j]  = af[i] * bf[j];
                    else        c2[i][j] += af[i] * bf[j];
                }
        }
#pragma unroll
        for (int i = 0; i < 8; ++i)
#pragma unroll
            for (int j = 0; j < 8; ++j) acc[i][j] += c2[i][j];
    }

    // ---- write logits to LDS score tile ----
    __syncthreads();
#pragma unroll
    for (int i = 0; i < 8; ++i) {
        const int r = (i < 4) ? ((ty << 2) + i) : (32 + (ty << 2) + i - 4);
#pragma unroll
        for (int j = 0; j < 8; ++j) {
            const int c = (j < 4) ? ((tx << 2) + j) : (128 + (tx << 2) + j - 4);
            Sc[r * SC_S + c] = acc[i][j];
        }
    }
    __syncthreads();

    // ---- routing: one lane per row (wave 0) ----
    if (tid < BM) {
        float* sc = &Sc[tid * SC_S];
        // sigmoid in place (reference top-ks sigmoid values)
        for (int e = 0; e < E; ++e) {
            const float v = sc[e];
            sc[e] = 1.0f / (1.0f + expf(-v));
        }
        // group maxes
        float gmax[NG];
#pragma unroll
        for (int g = 0; g < NG; ++g) {
            float m = -INFINITY;
            for (int j = 0; j < GS; ++j) m = fmaxf(m, sc[g * GS + j]);
            gmax[g] = m;
        }
        // top-4 groups (strict > + ascending scan == jax lower-index tie-break)
        int cmask = 0;
#pragma unroll
        for (int it = 0; it < TOPK_G; ++it) {
            float best = -INFINITY; int bg = 0;
#pragma unroll
            for (int g = 0; g < NG; ++g) {
                const bool free_g = ((cmask >> g) & 1) == 0;
                if (free_g && gmax[g] > best) { best = gmax[g]; bg = g; }
            }
            cmask |= (1 << bg);
        }
        // mask out non-chosen groups
#pragma unroll
        for (int g = 0; g < NG; ++g) {
            if (((cmask >> g) & 1) == 0) {
                for (int j = 0; j < GS; ++j) sc[g * GS + j] = -INFINITY;
            }
        }
        // top-8 selection, descending, lower-index ties
        float vals[TOPK]; int idxs[TOPK];
        for (int it = 0; it < TOPK; ++it) {
            float best = -INFINITY; int bi = 0;
            for (int e = 0; e < E; ++e) {
                const float v = sc[e];
                if (v > best) { best = v; bi = e; }
            }
            vals[it] = best; idxs[it] = bi;
            sc[bi] = -INFINITY;
        }
        // normalize * route_scale
        float s = 0.0f;
#pragma unroll
        for (int k = 0; k < TOPK; ++k) s += vals[k];
        const float scale = 2.5f / s;

        float* ow = out + (size_t)(row0 + tid) * TOPK;
        float* oi = out + (size_t)T * TOPK + (size_t)(row0 + tid) * TOPK;
#pragma unroll
        for (int k = 0; k < TOPK; ++k) {
            ow[k] = vals[k] * scale;
            oi[k] = (float)idxs[k];   // harness compares output 1 as float values
        }
    }
}

extern "C" void kernel_launch(void* const* d_in, const int* in_sizes, int n_in,
                              void* d_out, int out_size, void* d_ws, size_t ws_size,
                              hipStream_t stream) {
    const float* x = (const float*)d_in[0];
    const float* w = (const float*)d_in[1];
    float* out = (float*)d_out;
    (void)in_sizes; (void)n_in; (void)out_size; (void)d_ws; (void)ws_size;
    gate_fused<<<dim3(T / BM), dim3(NT), 0, stream>>>(x, w, out);
}